// Round 11
// baseline (9113.643 us; speedup 1.0000x reference)
//
#include <hip/hip_runtime.h>
#include <stdint.h>

constexpr int D_  = 1024;  // embedding dim
constexpr int E_  = 64;    // experts
constexpr int N_  = 1024;  // B*S tokens
constexpr int TG  = 32;    // tokens per pass (max bucket slice)
constexpr int CS  = 16;    // column slices (blocks per expert)
constexpr int CPB = 64;    // cols per block (1 col per lane)
constexpr int BK  = 32;    // k-rows staged per step
constexpr int NS  = D_ / BK;   // 32 steps

// direct global->LDS staging: no register consumer, so no vmcnt-ordering
// poison -- the only drain is the per-step barrier, hidden under compute.
#define GLDS16(g, l)                                                  \
  __builtin_amdgcn_global_load_lds(                                   \
      (const __attribute__((address_space(1))) void*)(g),             \
      (__attribute__((address_space(3))) void*)(l), 16, 0, 0)

// Block = (col-slice cs, expert e). 4 waves = 4 K-QUARTERS (wave wv owns 8 of
// the 32 staged k-rows, for ALL tokens) -- every wave computes for any bucket
// size T, unlike the round-10 token-quarter split that idled half the waves at
// typical T=16. Staging (identical geometry to round 10, verified): per step,
// W-tile 32x64 + x-tile 32x32 via global_load_lds, double-buffered, one vmcnt
// drain per step at the barrier. Compute: w lane-consecutive b32 (conflict-
// free), x wave-uniform b128 broadcast, quad-guarded token loop (<=4 LDS
// loads per guard region -> no pressure blowup). Cross-wave k-reduce once per
// pass through an 8 KB lane-consecutive red buffer.
__global__ __launch_bounds__(256, 4) void fused_moe_kernel(
    const float* __restrict__ x, const int* __restrict__ urls,
    const float* __restrict__ trans, const float* __restrict__ bias,
    float* __restrict__ out) {
  __shared__ __align__(16) float wl[2][BK * CPB];  // 2 x 8 KB
  __shared__ __align__(16) float xs[2][TG * BK];   // 2 x 4 KB
  __shared__ float red[TG][CPB];                   // 8 KB
  __shared__ int toksL[N_ + TG];                   // 4.1 KB zero-padded
  __shared__ int cntS;

  const int tid  = threadIdx.x;
  const int lane = tid & 63;
  const int wv   = tid >> 6;   // wave id = k-quarter
  const int cs   = blockIdx.x;
  const int e    = blockIdx.y;
  const int c0   = cs * CPB;

  // ---- in-block bucketing ----
  for (int i = tid; i < N_ + TG; i += 256) toksL[i] = 0;
  if (tid == 0) cntS = 0;
  __syncthreads();
  for (int i = tid; i < N_; i += 256)
    if (urls[i] == e) { int p = atomicAdd(&cntS, 1); toksL[p] = i; }
  __syncthreads();
  const int Ttot = cntS;
  if (Ttot == 0) return;  // uniform

  const float* __restrict__ tr = trans + (size_t)e * D_ * D_ + c0;
  const float bv = bias[(size_t)e * D_ + c0 + lane];

  // staging geometry (fixed per thread; verified in round 10):
  const int wrow0 = tid >> 4, wc4 = tid & 15;  // W: row 16j+(tid>>4), col4
  const int xslot = tid >> 3, xr4 = tid & 7;   // x: slot tid>>3, k4 tid&7
  const int kq = wv * (BK / 4);                // my 8 k-rows within the tile

  for (int beg = 0; beg < Ttot; beg += TG) {
    const int T  = (Ttot - beg < TG) ? (Ttot - beg) : TG;
    const int nQ = (T + 3) >> 2;
    const int xTokRow = toksL[beg + xslot];  // padded slots -> token 0 (safe)

    float acc[TG];
#pragma unroll
    for (int t = 0; t < TG; ++t) acc[t] = 0.f;

#define STAGE(s, b) do {                                                \
    const int _k0 = (s) * BK;                                           \
    GLDS16(tr + (size_t)(_k0 + wrow0) * D_ + wc4 * 4,                   \
           &wl[b][(wv * 64) * 4]);                                      \
    GLDS16(tr + (size_t)(_k0 + 16 + wrow0) * D_ + wc4 * 4,              \
           &wl[b][(256 + wv * 64) * 4]);                                \
    GLDS16(x + ((size_t)xTokRow << 10) + _k0 + xr4 * 4,                 \
           &xs[b][(wv * 64) * 4]);                                      \
  } while (0)

    STAGE(0, 0);
    __syncthreads();  // prologue drain (once per pass)

    for (int s = 0; s < NS; ++s) {
      const int cur = s & 1;
      if (s + 1 < NS) STAGE(s + 1, cur ^ 1);  // prefetch: no reg consumer
      const float* __restrict__ wb = &wl[cur][0];
      const float* __restrict__ xb = &xs[cur][0];
#pragma unroll
      for (int rb = 0; rb < BK / 16; ++rb) {  // 2 x 4 of my 8 k-rows
        const int rr = kq + rb * 4;
        const float w0 = wb[(rr + 0) * CPB + lane];
        const float w1 = wb[(rr + 1) * CPB + lane];
        const float w2 = wb[(rr + 2) * CPB + lane];
        const float w3 = wb[(rr + 3) * CPB + lane];
#pragma unroll
        for (int q = 0; q < TG / 4; ++q) {
          if (q < nQ) {  // uniform guard: <=4 LDS loads per region
#pragma unroll
            for (int j = 0; j < 4; ++j) {
              const int t = q * 4 + j;
              const float4 xv = *(const float4*)&xb[t * BK + rr];  // broadcast
              acc[t] += xv.x * w0 + xv.y * w1 + xv.z * w2 + xv.w * w3;
            }
          }
        }
      }
      __syncthreads();  // single vmcnt drain per step, hidden under compute
    }
#undef STAGE

    // ---- cross-wave k-reduce: 4 sequential accumulate rounds into red ----
    for (int g = 0; g < 4; ++g) {
      if (wv == g) {
#pragma unroll
        for (int t = 0; t < TG; ++t) {
          if (t < T) {
            if (g == 0) red[t][lane] = acc[t];
            else        red[t][lane] += acc[t];
          }
        }
      }
      __syncthreads();
    }

    // ---- bias + tanh + store (slots interleaved across waves) ----
#pragma unroll
    for (int j = 0; j < 8; ++j) {
      const int slot = wv + 4 * j;
      if (slot < T) {
        const int tok = toksL[beg + slot];
        out[((size_t)tok << 10) + c0 + lane] = tanhf(red[slot][lane] + bv);
      }
    }
    // no trailing barrier needed: next pass touches wl/xs (last read 2
    // barriers ago) and toksL (read-only since bucketing), never red.
  }
}

extern "C" void kernel_launch(void* const* d_in, const int* in_sizes, int n_in,
                              void* d_out, int out_size, void* d_ws, size_t ws_size,
                              hipStream_t stream) {
  const float* x     = (const float*)d_in[0];
  const int*   urls  = (const int*)d_in[1];
  const float* trans = (const float*)d_in[2];
  const float* bias  = (const float*)d_in[3];
  float* out = (float*)d_out;

  dim3 grid(CS, E_);
  fused_moe_kernel<<<grid, 256, 0, stream>>>(x, urls, trans, bias, out);
}